// Round 7
// baseline (181.235 us; speedup 1.0000x reference)
//
#include <hip/hip_runtime.h>
#include <math.h>

#define C 10
#define BLOCK 256
#define NBLOCKS 2048          // 8 blocks/CU (10 KB LDS, 48 VGPR) -> full 32-wave occupancy
#define TILE_ROWS 256
#define TILE_ELEMS (TILE_ROWS * C)   // 2560 floats = 10 KB LDS
#define NF4 (TILE_ELEMS / 4)         // 640 float4 per tile
#define NSTATS (3 * C)               // 30: s1[10], s2[10], slogp[10]

// ws layout: [0..256) counter+pad (zeroed by memsetAsync), [256..) partials SoA [30][NBLOCKS]

// ---------------- row accumulate (softmax sufficient statistics) ----------------

__device__ __forceinline__ void accum_row(const float* __restrict__ row,
                                          float* __restrict__ s1,
                                          float* __restrict__ s2,
                                          float* __restrict__ sl) {
  float v[C];
#pragma unroll
  for (int c = 0; c < C; c++) v[c] = row[c];
  float mx = v[0];
#pragma unroll
  for (int c = 1; c < C; c++) mx = fmaxf(mx, v[c]);
  float e[C], se = 0.f;
#pragma unroll
  for (int c = 0; c < C; c++) { v[c] -= mx; e[c] = __expf(v[c]); se += e[c]; }
  float inv = 1.0f / se;
  float lse = __logf(se);
#pragma unroll
  for (int c = 0; c < C; c++) {
    float p = e[c] * inv;
    s1[c] += p;
    s2[c] = fmaf(p, p, s2[c]);
    sl[c] += v[c] - lse;              // log p = (x - mx) - lse
  }
}

// ---------------- digamma+trigamma, fixed 8-step recurrence (ILP) ----------------

__device__ __forceinline__ void digtri8(double x, double& dg, double& tg) {
  double i0 = 1.0 / x,         i1 = 1.0 / (x + 1.0);
  double i2 = 1.0 / (x + 2.0), i3 = 1.0 / (x + 3.0);
  double i4 = 1.0 / (x + 4.0), i5 = 1.0 / (x + 5.0);
  double i6 = 1.0 / (x + 6.0), i7 = 1.0 / (x + 7.0);
  double rd = (i0 + i1) + (i2 + i3) + ((i4 + i5) + (i6 + i7));
  double rt = (i0 * i0 + i1 * i1) + (i2 * i2 + i3 * i3) +
              ((i4 * i4 + i5 * i5) + (i6 * i6 + i7 * i7));
  double y = x + 8.0;
  double yi = 1.0 / y, f = yi * yi;
  dg = log(y) - 0.5 * yi
     - f * (1.0 / 12 - f * (1.0 / 120 - f * (1.0 / 252 - f * (1.0 / 240 - f * (1.0 / 132)))))
     - rd;
  tg = rt + yi + 0.5 * f
     + f * yi * (1.0 / 6 - f * (1.0 / 30 - f * (1.0 / 42 - f * (1.0 / 30))));
}

__device__ __forceinline__ double wsum16(double v) {
#pragma unroll
  for (int off = 1; off < 16; off <<= 1) v += __shfl_xor(v, off);
  return v;
}

// ---------------- fused: stats -> partials -> last-block reduce + Newton ----------------

__global__ __launch_bounds__(BLOCK) void dir_fused_kernel(
    const float* __restrict__ x, unsigned* __restrict__ counter,
    float* __restrict__ partials, float* __restrict__ out,
    int nrows, int ntiles, int tailStart, int nblocks) {
  __shared__ float tile[TILE_ELEMS];
  __shared__ float red[4][NSTATS];
  __shared__ double tot[NSTATS];
  __shared__ int lastFlag;
  const int tid = threadIdx.x;

  float s1[C], s2[C], sl[C];
#pragma unroll
  for (int c = 0; c < C; c++) { s1[c] = 0.f; s2[c] = 0.f; sl[c] = 0.f; }

  for (int t = blockIdx.x; t < ntiles; t += nblocks) {
    const float4* __restrict__ src = (const float4*)(x + (size_t)t * TILE_ELEMS);
    float4* dst = (float4*)tile;
#pragma unroll
    for (int i = tid; i < NF4; i += BLOCK)      // 2-3 float4 per thread
      dst[i] = src[i];
    __syncthreads();
    accum_row(tile + (size_t)tid * C, s1, s2, sl);   // 1 row per thread
    __syncthreads();
  }

  if (blockIdx.x == nblocks - 1) {              // tail rows (<TILE_ROWS)
    for (int rr = tailStart + tid; rr < nrows; rr += BLOCK)
      accum_row(x + (size_t)rr * C, s1, s2, sl);
  }

  // block reduction: wave shuffle, cross-wave via LDS
  const int lane = tid & 63;
  const int wave = tid >> 6;
#pragma unroll
  for (int c = 0; c < C; c++) {
    float v1 = s1[c], v2 = s2[c], v3 = sl[c];
#pragma unroll
    for (int off = 32; off >= 1; off >>= 1) {
      v1 += __shfl_down(v1, off);
      v2 += __shfl_down(v2, off);
      v3 += __shfl_down(v3, off);
    }
    if (lane == 0) {
      red[wave][c] = v1;
      red[wave][C + c] = v2;
      red[wave][2 * C + c] = v3;
    }
  }
  __syncthreads();
  if (tid < NSTATS) {
    float totf = red[0][tid] + red[1][tid] + red[2][tid] + red[3][tid];
    partials[(size_t)tid * nblocks + blockIdx.x] = totf;   // distinct addrs, no contention
  }
  __syncthreads();                      // drains stores (vmcnt) before fence
  if (tid == 0) {
    __threadfence();                    // release: partials visible at coherence point
    unsigned old = atomicAdd(counter, 1u);
    lastFlag = (old == (unsigned)(nblocks - 1)) ? 1 : 0;
  }
  __syncthreads();
  if (!lastFlag) return;

  // ---- last-finishing block: reduce partials (8 lanes per series, agent-scope loads) ----
  {
    const int j = tid >> 3;             // series 0..31 (30 active)
    const int k = tid & 7;
    double s = 0.0;
    if (j < NSTATS) {
      const float* __restrict__ base = partials + (size_t)j * nblocks;
#pragma unroll 16
      for (int b = k; b < nblocks; b += 8)
        s += (double)__hip_atomic_load(&base[b], __ATOMIC_RELAXED, __HIP_MEMORY_SCOPE_AGENT);
    }
#pragma unroll
    for (int off = 1; off < 8; off <<= 1) s += __shfl_xor(s, off);  // 8-lane group reduce
    if (j < NSTATS && k == 0) tot[j] = s;
  }
  __syncthreads();

  // ---- Newton on lanes 0..15 (lane = channel, 10 active) ----
  if (tid < 16) {
    const int c = tid;
    const bool act = (c < C);
    const double n = (double)nrows;
    double m1 = 0.0, m2 = 0.0, lpa = 0.0;
    if (act) {
      m1 = tot[c] / n;
      m2 = tot[C + c] / n;
      lpa = tot[2 * C + c] / n;
    }
    double ratio = act ? (m1 - m2) / (m2 - m1 * m1) : 0.0;
    double rmean = wsum16(ratio) / (double)C;
    double a = act ? m1 * rmean : 0.0;

    double diff = 1e30;
    for (int k = 0; k < 100 && diff >= 1e-3; k++) {
      double S = wsum16(a);             // lanes 10..15 hold 0
      double dgl, tgl;                  // lanes 0..9: digtri(a); lane 10+: digtri(S)
      digtri8(act ? a : S, dgl, tgl);
      double dgS = __shfl(dgl, 10);
      double tgS = __shfl(tgl, 10);
      double g = act ? (dgS - dgl + lpa) * n : 0.0;
      double qinv = act ? (-1.0) / (n * tgl) : 0.0;
      double z = n * tgS;
      double num = wsum16(g * qinv);
      double den = 1.0 / z + wsum16(qinv);
      double b = num / den;
      double anew = act ? a - (g - b) * qinv : 0.0;
      diff = wsum16(fabs(anew - a));
      a = anew;
    }
    if (act) out[c] = (float)a;
  }
}

// ---------------- launch ----------------

extern "C" void kernel_launch(void* const* d_in, const int* in_sizes, int n_in,
                              void* d_out, int out_size, void* d_ws, size_t ws_size,
                              hipStream_t stream) {
  const float* x = (const float*)d_in[0];
  const int total = in_sizes[0];
  const int nrows = total / C;
  const int ntiles = nrows / TILE_ROWS;
  const int tailStart = ntiles * TILE_ROWS;

  int grid = NBLOCKS;
  size_t need = 256 + (size_t)NSTATS * grid * sizeof(float);
  if (need > ws_size) {
    grid = (int)((ws_size - 256) / (NSTATS * sizeof(float)));
    if (grid < 1) grid = 1;
  }

  unsigned* counter = (unsigned*)d_ws;
  float* partials = (float*)((char*)d_ws + 256);

  hipMemsetAsync(d_ws, 0, 256, stream);   // zero counter
  dir_fused_kernel<<<grid, BLOCK, 0, stream>>>(
      x, counter, partials, (float*)d_out, nrows, ntiles, tailStart, grid);
}

// Round 8
// 122.724 us; speedup vs baseline: 1.4768x; 1.4768x over previous
//
#include <hip/hip_runtime.h>
#include <math.h>

#define C 10
#define BLOCK 256
#define NBLOCKS 1024          // 4 blocks/CU (40 KB dbuf LDS); pipeline, not residency, hides latency
#define TILE_ROWS 512
#define TILE_ELEMS (TILE_ROWS * C)   // 5120 floats = 20 KB per buffer
#define NSTATS (3 * C)               // 30 series: s1[10], s2[10], slogp[10]

// ---------------- row accumulate (softmax sufficient statistics) ----------------

__device__ __forceinline__ void accum_row(const float* __restrict__ row,
                                          float* __restrict__ s1,
                                          float* __restrict__ s2,
                                          float* __restrict__ sl) {
  float v[C];
#pragma unroll
  for (int c = 0; c < C; c++) v[c] = row[c];
  float mx = v[0];
#pragma unroll
  for (int c = 1; c < C; c++) mx = fmaxf(mx, v[c]);
  float e[C], se = 0.f;
#pragma unroll
  for (int c = 0; c < C; c++) { v[c] -= mx; e[c] = __expf(v[c]); se += e[c]; }
  float inv = 1.0f / se;
  float lse = __logf(se);
#pragma unroll
  for (int c = 0; c < C; c++) {
    float p = e[c] * inv;
    s1[c] += p;
    s2[c] = fmaf(p, p, s2[c]);
    sl[c] += v[c] - lse;              // log p = (x - mx) - lse
  }
}

// ---------------- Kernel 1: software-pipelined stats ----------------
// Register double-buffer: tile t+1's global loads are issued right after tile t's
// LDS writes and stay IN FLIGHT across tile t's compute. Barriers are raw s_barrier
// (lgkm-drain only) so they never drain vmcnt — the structural fix for the
// stage->vmcnt(0)->barrier serial-latency stall seen in R5/R7 counters.

__global__ __launch_bounds__(BLOCK) void dir_stats_kernel(
    const float* __restrict__ x, float* __restrict__ partials,
    int nrows, int ntiles, int tailStart, int nblocks) {
  __shared__ float buf[2][TILE_ELEMS];   // 2 x 20 KB
  __shared__ float red[4][NSTATS];
  const int tid = threadIdx.x;

  float s1[C], s2[C], sl[C];
#pragma unroll
  for (int c = 0; c < C; c++) { s1[c] = 0.f; s2[c] = 0.f; sl[c] = 0.f; }

  // prologue: prefetch first tile into registers (5 float4 per thread, coalesced)
  float4 r0, r1, r2, r3, r4;
  int t = blockIdx.x;
  if (t < ntiles) {
    const float4* __restrict__ src = (const float4*)(x + (size_t)t * TILE_ELEMS);
    r0 = src[tid];        r1 = src[tid + 256];  r2 = src[tid + 512];
    r3 = src[tid + 768];  r4 = src[tid + 1024];
  }

  int phase = 0;
  for (; t < ntiles; t += nblocks, phase ^= 1) {
    // barrier A: readers of buf[phase] (iter t-2) are done. No vmcnt drain.
    asm volatile("s_barrier" ::: "memory");

    float4* dst = (float4*)buf[phase];
    dst[tid]       = r0;  dst[tid + 256] = r1;  dst[tid + 512]  = r2;
    dst[tid + 768] = r3;  dst[tid + 1024] = r4;      // compiler waits vmcnt here only

    // issue NEXT tile's loads now — in flight across the whole compute phase
    int tn = t + nblocks;
    if (tn < ntiles) {
      const float4* __restrict__ src = (const float4*)(x + (size_t)tn * TILE_ELEMS);
      r0 = src[tid];        r1 = src[tid + 256];  r2 = src[tid + 512];
      r3 = src[tid + 768];  r4 = src[tid + 1024];
    }

    // barrier B: ds_writes visible to all waves. lgkm drain only — vmcnt untouched.
    asm volatile("s_waitcnt lgkmcnt(0)\n\ts_barrier" ::: "memory");

    accum_row(buf[phase] + (size_t)tid * C, s1, s2, sl);
    accum_row(buf[phase] + (size_t)(256 + tid) * C, s1, s2, sl);
  }

  if (blockIdx.x == nblocks - 1) {        // tail rows (<TILE_ROWS)
    for (int rr = tailStart + tid; rr < nrows; rr += BLOCK)
      accum_row(x + (size_t)rr * C, s1, s2, sl);
  }

  // block reduction: wave shuffle, then cross-wave via LDS
  const int lane = tid & 63;
  const int wave = tid >> 6;
#pragma unroll
  for (int c = 0; c < C; c++) {
    float v1 = s1[c], v2 = s2[c], v3 = sl[c];
#pragma unroll
    for (int off = 32; off >= 1; off >>= 1) {
      v1 += __shfl_down(v1, off);
      v2 += __shfl_down(v2, off);
      v3 += __shfl_down(v3, off);
    }
    if (lane == 0) {
      red[wave][c] = v1;
      red[wave][C + c] = v2;
      red[wave][2 * C + c] = v3;
    }
  }
  __syncthreads();
  if (tid < NSTATS) {
    float tot = red[0][tid] + red[1][tid] + red[2][tid] + red[3][tid];
    partials[(size_t)tid * nblocks + blockIdx.x] = tot;   // SoA over blocks
  }
}

// ---------------- Kernel 2: MLP-parallel reduce + Newton (fp64) ----------------
// Separate dispatch = free bulk cross-XCD coherence -> plain coalesced loads (fast).

__device__ __forceinline__ void digtri8(double x, double& dg, double& tg) {
  double i0 = 1.0 / x,         i1 = 1.0 / (x + 1.0);
  double i2 = 1.0 / (x + 2.0), i3 = 1.0 / (x + 3.0);
  double i4 = 1.0 / (x + 4.0), i5 = 1.0 / (x + 5.0);
  double i6 = 1.0 / (x + 6.0), i7 = 1.0 / (x + 7.0);
  double rd = (i0 + i1) + (i2 + i3) + ((i4 + i5) + (i6 + i7));
  double rt = (i0 * i0 + i1 * i1) + (i2 * i2 + i3 * i3) +
              ((i4 * i4 + i5 * i5) + (i6 * i6 + i7 * i7));
  double y = x + 8.0;
  double yi = 1.0 / y, f = yi * yi;
  dg = log(y) - 0.5 * yi
     - f * (1.0 / 12 - f * (1.0 / 120 - f * (1.0 / 252 - f * (1.0 / 240 - f * (1.0 / 132)))))
     - rd;
  tg = rt + yi + 0.5 * f
     + f * yi * (1.0 / 6 - f * (1.0 / 30 - f * (1.0 / 42 - f * (1.0 / 30))));
}

__device__ __forceinline__ double wsum16(double v) {
#pragma unroll
  for (int off = 1; off < 16; off <<= 1) v += __shfl_xor(v, off);
  return v;
}

__global__ __launch_bounds__(1024) void dir_newton_kernel(
    const float* __restrict__ partials, float* __restrict__ out,
    int nparts, double nrows) {
  __shared__ double tot[NSTATS];
  const int tid = threadIdx.x;

  {
    const int j = tid >> 5;        // series (30 active of 32)
    const int k = tid & 31;
    double s = 0.0;
    if (j < NSTATS) {
      const float* __restrict__ base = partials + (size_t)j * nparts;
#pragma unroll 8
      for (int b = k; b < nparts; b += 32)
        s += (double)base[b];
    }
#pragma unroll
    for (int off = 16; off >= 1; off >>= 1) s += __shfl_xor(s, off);
    if (j < NSTATS && k == 0) tot[j] = s;
  }
  __syncthreads();

  if (tid < 16) {
    const int c = tid;
    const bool act = (c < C);
    const double n = nrows;
    double m1 = 0.0, m2 = 0.0, lpa = 0.0;
    if (act) {
      m1 = tot[c] / n;
      m2 = tot[C + c] / n;
      lpa = tot[2 * C + c] / n;
    }
    double ratio = act ? (m1 - m2) / (m2 - m1 * m1) : 0.0;
    double rmean = wsum16(ratio) / (double)C;
    double a = act ? m1 * rmean : 0.0;

    double diff = 1e30;
    for (int k = 0; k < 100 && diff >= 1e-3; k++) {
      double S = wsum16(a);             // lanes 10..15 hold 0
      double dgl, tgl;                  // lanes 0..9: digtri(a); lane 10+: digtri(S)
      digtri8(act ? a : S, dgl, tgl);
      double dgS = __shfl(dgl, 10);
      double tgS = __shfl(tgl, 10);
      double g = act ? (dgS - dgl + lpa) * n : 0.0;
      double qinv = act ? (-1.0) / (n * tgl) : 0.0;
      double z = n * tgS;
      double num = wsum16(g * qinv);
      double den = 1.0 / z + wsum16(qinv);
      double b = num / den;
      double anew = act ? a - (g - b) * qinv : 0.0;
      diff = wsum16(fabs(anew - a));
      a = anew;
    }
    if (act) out[c] = (float)a;
  }
}

// ---------------- launch ----------------

extern "C" void kernel_launch(void* const* d_in, const int* in_sizes, int n_in,
                              void* d_out, int out_size, void* d_ws, size_t ws_size,
                              hipStream_t stream) {
  const float* x = (const float*)d_in[0];
  const int total = in_sizes[0];
  const int nrows = total / C;
  const int ntiles = nrows / TILE_ROWS;
  const int tailStart = ntiles * TILE_ROWS;

  int grid = NBLOCKS;
  size_t need = (size_t)NSTATS * grid * sizeof(float);
  if (need > ws_size) {
    grid = (int)(ws_size / (NSTATS * sizeof(float)));
    if (grid < 1) grid = 1;
  }

  float* partials = (float*)d_ws;
  dir_stats_kernel<<<grid, BLOCK, 0, stream>>>(x, partials, nrows, ntiles, tailStart, grid);
  dir_newton_kernel<<<1, 1024, 0, stream>>>(partials, (float*)d_out, grid, (double)nrows);
}